// Round 6
// baseline (175.299 us; speedup 1.0000x reference)
//
#include <hip/hip_runtime.h>
#include <math.h>

// Problem constants
#define NQ     25      // number of query images (= n_support)
#define NWAY   5
#define KSHOT  5
#define CC     640     // channels (k-dim of S gemm; 640 = 20*32)
#define HW     196     // 14*14
#define NSL    980     // NWAY*HW support locations
#define NSLP   992     // padded K for M-gemm (31*32)
#define RPQ    208     // padded row count per query (13*16)
#define GAMMA  20.0f
#define GAMMA2 10.0f
#define NITER  8       // ||M||_1 = 0.25 -> tail 0.25^9/0.75 ~ 5e-6, threshold 1.77e-2
#define MSTRIDE 204    // LDS row stride (floats): 816B, 16B-aligned, conflict-free b128

typedef __bf16 bf16;
typedef __attribute__((ext_vector_type(8))) __bf16 bf16x8;
typedef __attribute__((ext_vector_type(4))) float f32x4;

// ---------------------------------------------------------------------------
// K1: prototype mean + per-location L2 normalization -> TRANSPOSED bf16.
// qnbt[q][m][c] (rows padded to RPQ), snbt[j][c] (rows padded to NSLP).
// ---------------------------------------------------------------------------
__global__ __launch_bounds__(256) void k_norm(const float* __restrict__ feat,
                                              bf16* __restrict__ qnbt,
                                              bf16* __restrict__ snbt) {
    const int by = blockIdx.y;
    const int lx = threadIdx.x & 15;
    const int cg = threadIdx.x >> 4;
    const int l  = blockIdx.x * 16 + lx;
    const bool act = (l < HW);
    const int c0 = cg * 40;
    __shared__ float pr[16][17];

    float xv[40];
    float ss = 0.f;
    if (by < NQ) {
        const float* f = feat + (size_t)(NQ + by) * CC * HW;
#pragma unroll
        for (int i = 0; i < 40; ++i) {
            float x = act ? f[(c0 + i) * HW + l] : 0.f;
            xv[i] = x; ss += x * x;
        }
    } else {
        const int s = by - NQ;
        const float* f = feat + (size_t)(NQ + s * KSHOT) * CC * HW;
        const size_t img = (size_t)CC * HW;
#pragma unroll
        for (int i = 0; i < 40; ++i) {
            float m = 0.f;
            if (act) {
                const float* p = f + (c0 + i) * HW + l;
                m = 0.2f * (p[0] + p[img] + p[2 * img] + p[3 * img] + p[4 * img]);
            }
            xv[i] = m; ss += m * m;
        }
    }
    pr[cg][lx] = ss;
    __syncthreads();
    if (cg == 0) {
        float a = 0.f;
#pragma unroll
        for (int k = 0; k < 16; ++k) a += pr[k][lx];
        pr[0][lx] = 1.f / (1e-16f + sqrtf(a));
    }
    __syncthreads();
    const float inv = pr[0][lx];
    if (act) {
        bf16* o = (by < NQ) ? (qnbt + ((size_t)by * RPQ + l) * CC)
                            : (snbt + ((size_t)(by - NQ) * HW + l) * CC);
#pragma unroll
        for (int i = 0; i < 40; ++i) o[c0 + i] = (bf16)(xv[i] * inv);
    }
}

// ---------------------------------------------------------------------------
// K2: S[q][m][j] = sum_c qnbt[q][m][c] * snbt[j][c]   via 16x16x32 bf16 MFMA.
// One wave per 64x64 output tile (4x4 sub-tiles of 16x16) -> 32 FLOP/B.
// grid (16 n-tiles, 4 m-tiles, 25 q), 64 threads.
// ---------------------------------------------------------------------------
__global__ __launch_bounds__(64) void k_sgemm(const bf16* __restrict__ qnbt,
                                              const bf16* __restrict__ snbt,
                                              float* __restrict__ S) {
    const int q  = blockIdx.z;
    const int mt = blockIdx.y;
    const int nt = blockIdx.x;
    const int l  = threadIdx.x;
    const int lo = l & 15, hi = l >> 4;
    const bf16* Ap[4];
    const bf16* Bp[4];
#pragma unroll
    for (int mi = 0; mi < 4; ++mi)
        Ap[mi] = qnbt + ((size_t)q * RPQ + mt * 64 + mi * 16 + lo) * CC + hi * 8;
#pragma unroll
    for (int ni = 0; ni < 4; ++ni)
        Bp[ni] = snbt + ((size_t)(nt * 64 + ni * 16 + lo)) * CC + hi * 8;

    f32x4 acc[4][4] = {};
#pragma unroll 2
    for (int k0 = 0; k0 < CC; k0 += 32) {
        bf16x8 a[4], b[4];
#pragma unroll
        for (int mi = 0; mi < 4; ++mi) a[mi] = *reinterpret_cast<const bf16x8*>(Ap[mi] + k0);
#pragma unroll
        for (int ni = 0; ni < 4; ++ni) b[ni] = *reinterpret_cast<const bf16x8*>(Bp[ni] + k0);
#pragma unroll
        for (int mi = 0; mi < 4; ++mi)
#pragma unroll
            for (int ni = 0; ni < 4; ++ni)
                acc[mi][ni] = __builtin_amdgcn_mfma_f32_16x16x32_bf16(a[mi], b[ni], acc[mi][ni], 0, 0, 0);
    }

    float* Sq = S + (size_t)q * HW * NSL;
#pragma unroll
    for (int mi = 0; mi < 4; ++mi) {
#pragma unroll
        for (int ni = 0; ni < 4; ++ni) {
            const int j = nt * 64 + ni * 16 + lo;
            if (j >= NSL) continue;
#pragma unroll
            for (int r = 0; r < 4; ++r) {
                int m = mt * 64 + mi * 16 + hi * 4 + r;
                if (m < HW) Sq[(size_t)m * NSL + j] = acc[mi][ni][r];
            }
        }
    }
}

// ---------------------------------------------------------------------------
// K3a: Ts[q][m][j] = softmax_j(GAMMA * S[qm][:]) -> bf16 (stride NSLP, pads 0)
//      + fused class row-sums R[q][s][m] (fp32).  One block per (q,m) row.
// ---------------------------------------------------------------------------
__global__ __launch_bounds__(256) void k_ts(const float* __restrict__ S,
                                            bf16* __restrict__ Ts,
                                            float* __restrict__ R) {
    const int qm = blockIdx.x;
    const int q = qm / HW, m = qm - q * HW;
    const float* row = S + (size_t)qm * NSL;
    bf16* orow = Ts + ((size_t)q * RPQ + m) * NSLP;
    const int t = threadIdx.x, lane = t & 63, wv = t >> 6;
    __shared__ float redm[4], reds[4], rred[NWAY][4];
    float x[4];
    float mx = -1e30f;
#pragma unroll
    for (int p = 0; p < 4; ++p) {
        int j = t + p * 256;
        x[p] = (j < NSL) ? row[j] : -1e30f;
        mx = fmaxf(mx, x[p]);
    }
    for (int d = 32; d; d >>= 1) mx = fmaxf(mx, __shfl_xor(mx, d));
    if (lane == 0) redm[wv] = mx;
    __syncthreads();
    mx = fmaxf(fmaxf(redm[0], redm[1]), fmaxf(redm[2], redm[3]));
    float e[4], sum = 0.f;
#pragma unroll
    for (int p = 0; p < 4; ++p) {
        e[p] = expf(GAMMA * (x[p] - mx));
        sum += e[p];
    }
    for (int d = 32; d; d >>= 1) sum += __shfl_xor(sum, d);
    if (lane == 0) reds[wv] = sum;
    __syncthreads();
    const float inv = 1.f / (reds[0] + reds[1] + reds[2] + reds[3]);
    float racc[NWAY];
#pragma unroll
    for (int s = 0; s < NWAY; ++s) racc[s] = 0.f;
#pragma unroll
    for (int p = 0; p < 4; ++p) {
        int j = t + p * 256;
        if (j < NSL) {
            float val = e[p] * inv;
            orow[j] = (bf16)val;
            int cls = j / HW;
#pragma unroll
            for (int s = 0; s < NWAY; ++s) racc[s] += (cls == s) ? val : 0.f;
        } else if (j < NSLP) {
            orow[j] = (bf16)0.f;   // zero K-pad (feeds k_mgemm)
        }
    }
#pragma unroll
    for (int s = 0; s < NWAY; ++s) {
        float a = racc[s];
        for (int d = 32; d; d >>= 1) a += __shfl_xor(a, d);
        if (lane == 0) rred[s][wv] = a;
    }
    __syncthreads();
    if (t < NWAY)
        R[((size_t)q * NWAY + t) * HW + m] =
            rred[t][0] + rred[t][1] + rred[t][2] + rred[t][3];
}

// ---------------------------------------------------------------------------
// K3b: Tq[q][m][j] = softmax over m of (GAMMA2 * S[q][:,j]) -> bf16, pads 0.
// grid (16, 25): 64 columns per block, 4 m-groups of 49; exp cached in regs.
// ---------------------------------------------------------------------------
__global__ __launch_bounds__(256) void k_tq(const float* __restrict__ S,
                                            bf16* __restrict__ Tq) {
    const int q  = blockIdx.y;
    const int tx = threadIdx.x & 63;
    const int tg = threadIdx.x >> 6;           // m-group 0..3
    const int j  = blockIdx.x * 64 + tx;
    const int m0 = tg * 49;
    const float* base = S + (size_t)q * HW * NSL;
    bf16* ob = Tq + (size_t)q * RPQ * NSLP;
    __shared__ float rmax[4][64], rsum[4][64];
    float xv[49];
    float mx = -1e30f;
    if (j < NSL) {
#pragma unroll
        for (int i = 0; i < 49; ++i) {
            xv[i] = base[(m0 + i) * NSL + j];
            mx = fmaxf(mx, xv[i]);
        }
    }
    rmax[tg][tx] = mx;
    __syncthreads();
    mx = fmaxf(fmaxf(rmax[0][tx], rmax[1][tx]), fmaxf(rmax[2][tx], rmax[3][tx]));
    float sum = 0.f;
    if (j < NSL) {
#pragma unroll
        for (int i = 0; i < 49; ++i) {
            xv[i] = expf(GAMMA2 * (xv[i] - mx));
            sum += xv[i];
        }
    }
    rsum[tg][tx] = sum;
    __syncthreads();
    const float inv = 1.f / (rsum[0][tx] + rsum[1][tx] + rsum[2][tx] + rsum[3][tx]);
    if (j < NSL) {
#pragma unroll
        for (int i = 0; i < 49; ++i) ob[(size_t)(m0 + i) * NSLP + j] = (bf16)(xv[i] * inv);
    } else if (j < NSLP) {
#pragma unroll
        for (int i = 0; i < 49; ++i) ob[(size_t)(m0 + i) * NSLP + j] = (bf16)0.f;
    }
}

// ---------------------------------------------------------------------------
// K4: M[q] = 0.25 * Tq[q] (196x992) * Ts[q]^T (992x196) via bf16 MFMA.
// One wave per 64x64 tile (4x4 of 16x16). grid (4 j, 4 i, 25 q), 64 threads.
// ---------------------------------------------------------------------------
__global__ __launch_bounds__(64) void k_mgemm(const bf16* __restrict__ Tq,
                                              const bf16* __restrict__ Ts,
                                              float* __restrict__ M) {
    const int q  = blockIdx.z;
    const int it = blockIdx.y;
    const int jt = blockIdx.x;
    const int l  = threadIdx.x;
    const int lo = l & 15, hi = l >> 4;
    const bf16* Ap[4];
    const bf16* Bp[4];
#pragma unroll
    for (int mi = 0; mi < 4; ++mi)
        Ap[mi] = Tq + ((size_t)q * RPQ + it * 64 + mi * 16 + lo) * NSLP + hi * 8;
#pragma unroll
    for (int ni = 0; ni < 4; ++ni)
        Bp[ni] = Ts + ((size_t)q * RPQ + jt * 64 + ni * 16 + lo) * NSLP + hi * 8;

    f32x4 acc[4][4] = {};
#pragma unroll 2
    for (int k0 = 0; k0 < NSLP; k0 += 32) {
        bf16x8 a[4], b[4];
#pragma unroll
        for (int mi = 0; mi < 4; ++mi) a[mi] = *reinterpret_cast<const bf16x8*>(Ap[mi] + k0);
#pragma unroll
        for (int ni = 0; ni < 4; ++ni) b[ni] = *reinterpret_cast<const bf16x8*>(Bp[ni] + k0);
#pragma unroll
        for (int mi = 0; mi < 4; ++mi)
#pragma unroll
            for (int ni = 0; ni < 4; ++ni)
                acc[mi][ni] = __builtin_amdgcn_mfma_f32_16x16x32_bf16(a[mi], b[ni], acc[mi][ni], 0, 0, 0);
    }

    float* Mq = M + (size_t)q * HW * HW;
#pragma unroll
    for (int mi = 0; mi < 4; ++mi) {
#pragma unroll
        for (int ni = 0; ni < 4; ++ni) {
            const int j = jt * 64 + ni * 16 + lo;
            if (j >= HW) continue;
#pragma unroll
            for (int r = 0; r < 4; ++r) {
                int i = it * 64 + mi * 16 + hi * 4 + r;
                if (i < HW) Mq[(size_t)i * HW + j] = 0.25f * acc[mi][ni][r];
            }
        }
    }
}

// ---------------------------------------------------------------------------
// K6: per-query Katz solve.  M in LDS (float4 rows, stride 204 -> conflict-
// free b128).  rhs computed in-kernel from Tq row sums (fuses old k_rhs).
// v <- rhs + M v  (NITER times); out[q][s] = (sum_m v[m]*R[s][m]) / total
// ---------------------------------------------------------------------------
__global__ __launch_bounds__(256) void k_solve2(const float* __restrict__ M,
                                               const bf16* __restrict__ Tq,
                                               const float* __restrict__ R,
                                               float* __restrict__ out) {
    const int q = blockIdx.x;
    __shared__ __align__(16) float Ms[HW * MSTRIDE];   // 159,936 B
    __shared__ __align__(16) float va[HW], vb[HW], rhsl[HW];
    __shared__ float cls[NWAY];
    const int t = threadIdx.x, lane = t & 63, wv = t >> 6;

    // --- load M (196x196 fp32) into strided LDS layout, coalesced float4 ---
    const float4* Mq4 = reinterpret_cast<const float4*>(M + (size_t)q * HW * HW);
    for (int idx4 = t; idx4 < HW * (HW / 4); idx4 += 256) {
        int i = idx4 / (HW / 4), c4 = idx4 - i * (HW / 4);
        *reinterpret_cast<float4*>(&Ms[i * MSTRIDE + 4 * c4]) = Mq4[idx4];
    }

    // --- rhs[m] = 1 + 0.5 * rowsum(Tq[q][m][:992]) (K-pads are zero) ---
    for (int m = wv; m < HW; m += 4) {
        const bf16x8* row = reinterpret_cast<const bf16x8*>(Tq + ((size_t)q * RPQ + m) * NSLP);
        float s = 0.f;
        for (int c = lane; c < NSLP / 8; c += 64) {
            bf16x8 v8 = row[c];
#pragma unroll
            for (int e = 0; e < 8; ++e) s += (float)v8[e];
        }
        for (int d = 32; d; d >>= 1) s += __shfl_xor(s, d);
        if (lane == 0) rhsl[m] = 1.f + 0.5f * s;
    }
    __syncthreads();

    float rr = 0.f;
    if (t < HW) { rr = rhsl[t]; va[t] = rr; }
    __syncthreads();

    // --- NITER x (v <- rhs + M v), float4 LDS matvec ---
    for (int it = 0; it < NITER; ++it) {
        const float* src = (it & 1) ? vb : va;
        float* dst = (it & 1) ? va : vb;
        if (t < HW) {
            const float4* Mr  = reinterpret_cast<const float4*>(&Ms[t * MSTRIDE]);
            const float4* sv4 = reinterpret_cast<const float4*>(src);
            float a = 0.f;
#pragma unroll 7
            for (int jc = 0; jc < HW / 4; ++jc) {
                float4 mv = Mr[jc];
                float4 sv = sv4[jc];
                a += mv.x * sv.x + mv.y * sv.y + mv.z * sv.z + mv.w * sv.w;
            }
            dst[t] = rr + a;
        }
        __syncthreads();
    }
    // NITER even -> result in va

    for (int s = wv; s < NWAY; s += 4) {
        float a = 0.f;
        const float* Rs = R + ((size_t)q * NWAY + s) * HW;
        for (int m = lane; m < HW; m += 64) a += va[m] * Rs[m];
        for (int d = 32; d; d >>= 1) a += __shfl_xor(a, d);
        if (lane == 0) cls[s] = a;
    }
    __syncthreads();
    if (t == 0) {
        float tot = cls[0] + cls[1] + cls[2] + cls[3] + cls[4];
        float invt = 1.f / tot;
        for (int s = 0; s < NWAY; ++s) out[q * NWAY + s] = cls[s] * invt;
    }
}

// ---------------------------------------------------------------------------
extern "C" void kernel_launch(void* const* d_in, const int* in_sizes, int n_in,
                              void* d_out, int out_size, void* d_ws, size_t ws_size,
                              hipStream_t stream) {
    const float* feat = (const float*)d_in[0];
    float* out = (float*)d_out;
    char* w = (char*)d_ws;

    // workspace layout (all offsets 16B-aligned)
    float* S    = (float*)w;  w += sizeof(float) * (size_t)NQ * HW * NSL;   // 19.21 MB
    bf16*  Ts   = (bf16*)w;   w += sizeof(bf16)  * (size_t)NQ * RPQ * NSLP; // 10.32 MB
    bf16*  Tq   = (bf16*)w;   w += sizeof(bf16)  * (size_t)NQ * RPQ * NSLP; // 10.32 MB
    bf16*  qnbt = (bf16*)w;   w += sizeof(bf16)  * (size_t)NQ * RPQ * CC;   //  6.66 MB
    bf16*  snbt = (bf16*)w;   w += sizeof(bf16)  * (size_t)NSLP * CC;       //  1.27 MB
    float* R    = (float*)w;  w += sizeof(float) * (size_t)NQ * NWAY * HW;
    // S is dead after both softmaxes -> M aliases S (0.96M floats <= 4.8M)
    float* M = S;

    k_norm  <<<dim3(13, NQ + NWAY), 256, 0, stream>>>(feat, qnbt, snbt);
    k_sgemm <<<dim3(16, 4, NQ), 64, 0, stream>>>(qnbt, snbt, S);
    k_ts    <<<NQ * HW, 256, 0, stream>>>(S, Ts, R);
    k_tq    <<<dim3(16, NQ), 256, 0, stream>>>(S, Tq);
    k_mgemm <<<dim3(4, 4, NQ), 64, 0, stream>>>(Tq, Ts, M);
    k_solve2<<<NQ, 256, 0, stream>>>(M, Tq, R, out);
}